// Round 3
// baseline (201.471 us; speedup 1.0000x reference)
//
#include <hip/hip_runtime.h>

typedef unsigned short u16;
typedef __attribute__((ext_vector_type(8))) short bf16x8;
typedef __attribute__((ext_vector_type(4))) float f32x4;

#define MFMA16(a, b, c) __builtin_amdgcn_mfma_f32_16x16x32_bf16((a), (b), (c), 0, 0, 0)
#define EXP2(x) __builtin_amdgcn_exp2f(x)

// Problem constants
#define S 2048
#define D 2048
#define NH 32
#define NKV 8
#define HD 64
#define QKV_N 3072  // (32 + 2*8) * 64

__device__ __forceinline__ u16 f2bf(float f) {
  unsigned int u = __float_as_uint(f);
  u += 0x7fffu + ((u >> 16) & 1u);
  return (u16)(u >> 16);
}

// async global->LDS, 16B per lane. LDS dest = wave-uniform base + lane*16.
__device__ __forceinline__ void glds16(const void* g, void* l) {
  __builtin_amdgcn_global_load_lds((const __attribute__((address_space(1))) unsigned int*)g,
                                   (__attribute__((address_space(3))) unsigned int*)l,
                                   16, 0, 0);
}

// ---- T12 primitives: pack f32 P-values to bf16 PV A-fragment in-register ----
__device__ __forceinline__ unsigned int cvtpk(float lo, float hi) {
  unsigned int r;
  asm("v_cvt_pk_bf16_f32 %0, %1, %2" : "=v"(r) : "v"(lo), "v"(hi));
  return r;
}
// swaps lanes[32:63] of a with lanes[0:31] of b (both regs updated)
__device__ __forceinline__ void swap32(unsigned int& a, unsigned int& b) {
  asm("v_permlane32_swap_b32 %0, %1" : "+v"(a), "+v"(b));
}
// swaps odd 16-lane rows of a with even 16-lane rows of b
__device__ __forceinline__ void swap16(unsigned int& a, unsigned int& b) {
  asm("v_permlane16_swap_b32 %0, %1" : "+v"(a), "+v"(b));
}
// Input: c0[r] = P[q=lr][k = t0*16 + 4*hi + r], c1[r] = same at t0*16+16.
// Output: bf16x8 A-fragment, elem j = P[q=lr][k = t0*16 + 8*hi + j].
__device__ __forceinline__ bf16x8 pack4(const f32x4 c0, const f32x4 c1) {
  unsigned int x0 = cvtpk(c0[0], c0[1]);  // {4hi,4hi+1}
  unsigned int x1 = cvtpk(c0[2], c0[3]);  // {4hi+2,4hi+3}
  unsigned int y0 = cvtpk(c1[0], c1[1]);  // {16+4hi,16+4hi+1}
  unsigned int y1 = cvtpk(c1[2], c1[3]);  // {16+4hi+2,16+4hi+3}
  swap32(x0, y0); swap16(x0, y0);  // x0 -> {8hi,8hi+1}, y0 -> {8hi+4,8hi+5}
  swap32(x1, y1); swap16(x1, y1);  // x1 -> {8hi+2,8hi+3}, y1 -> {8hi+6,8hi+7}
  union { bf16x8 v; unsigned int u[4]; } r;
  r.u[0] = x0; r.u[1] = x1; r.u[2] = y0; r.u[3] = y1;
  return r.v;
}

// ---------------------------------------------------------------- fused cast fp32 -> bf16 (all 3 inputs)
#define N1 (S * D / 4)
#define N2 (QKV_N * D / 4)
#define N3 (D * D / 4)
__global__ void cast_all(const float* __restrict__ hs, const float* __restrict__ wqkv,
                         const float* __restrict__ wo, u16* __restrict__ o1,
                         u16* __restrict__ o2, u16* __restrict__ o3) {
  int i = blockIdx.x * blockDim.x + threadIdx.x;
  const float* src;
  u16* dst;
  int idx;
  if (i < N1) { src = hs; dst = o1; idx = i; }
  else if (i < N1 + N2) { src = wqkv; dst = o2; idx = i - N1; }
  else if (i < N1 + N2 + N3) { src = wo; dst = o3; idx = i - N1 - N2; }
  else return;
  float4 v = ((const float4*)src)[idx];
  ushort4 o;
  o.x = f2bf(v.x); o.y = f2bf(v.y); o.z = f2bf(v.z); o.w = f2bf(v.w);
  ((ushort4*)dst)[idx] = o;
}

// ---------------------------------------------------------------- GEMM core: 128x64 tile, BK=64, glds dbuf
// One barrier per 64-wide K-step. XOR-SWIZZLED LDS layout: rows are 128 B =
// exactly 32 banks, so the naive layout puts all 16 rows of a fragment read
// on the same 4 banks (16-way conflict, ~5.7x per ds_read_b128 -- measured
// 1.4e7 SQ_LDS_BANK_CONFLICT in R8). global_load_lds forbids padding (dest
// is lane-contiguous), but the SOURCE is per-lane: stage global 16B-chunk
// (c ^ row&7) into physical chunk c. Readers XOR the chunk index with row&7:
// 16 rows -> 8 distinct chunks = all 32 banks, 2-way only (free, m136).
#define GEMM_MAINLOOP(A_, B_, K_, bm_, bn_)                                            \
  const int srowS = lane >> 3, scolS = ((lane & 7) ^ srowS) * 8;                       \
  const int aBase = wave * 32, bBase = wave * 16;                                      \
  const int qq = lane >> 4, sw = lr & 7;                                               \
  _Pragma("unroll") for (int c2 = 0; c2 < 4; ++c2)                                     \
      glds16(A_ + (size_t)(bm_ + aBase + c2 * 8 + srowS) * K_ + scolS,                 \
             &sA[0][aBase + c2 * 8][0]);                                               \
  _Pragma("unroll") for (int c2 = 0; c2 < 2; ++c2)                                     \
      glds16(B_ + (size_t)(bn_ + bBase + c2 * 8 + srowS) * K_ + scolS,                 \
             &sB[0][bBase + c2 * 8][0]);                                               \
  const int nk = K_ >> 6;                                                              \
  for (int it = 0; it < nk; ++it) {                                                    \
    const int buf = it & 1;                                                            \
    __syncthreads();                                                                   \
    if (it + 1 < nk) {                                                                 \
      const int k1 = (it + 1) << 6;                                                    \
      _Pragma("unroll") for (int c2 = 0; c2 < 4; ++c2)                                 \
          glds16(A_ + (size_t)(bm_ + aBase + c2 * 8 + srowS) * K_ + k1 + scolS,        \
                 &sA[buf ^ 1][aBase + c2 * 8][0]);                                     \
      _Pragma("unroll") for (int c2 = 0; c2 < 2; ++c2)                                 \
          glds16(B_ + (size_t)(bn_ + bBase + c2 * 8 + srowS) * K_ + k1 + scolS,        \
                 &sB[buf ^ 1][bBase + c2 * 8][0]);                                     \
    }                                                                                  \
    bf16x8 af[2][2], bfr[2][4];                                                        \
    _Pragma("unroll") for (int c = 0; c < 2; ++c) {                                    \
      const int pc = (((c << 2) | qq) ^ sw) * 8; /* swizzled chunk -> u16 offset */    \
      _Pragma("unroll") for (int i = 0; i < 2; ++i)                                    \
          af[c][i] = *(const bf16x8*)(&sA[buf][wr + i * 16 + lr][pc]);                 \
      _Pragma("unroll") for (int j = 0; j < 4; ++j)                                    \
          bfr[c][j] = *(const bf16x8*)(&sB[buf][j * 16 + lr][pc]);                     \
    }                                                                                  \
    _Pragma("unroll") for (int c = 0; c < 2; ++c)                                      \
        _Pragma("unroll") for (int i = 0; i < 2; ++i)                                  \
            _Pragma("unroll") for (int j = 0; j < 4; ++j)                              \
                acc[i][j] = MFMA16(af[c][i], bfr[c][j], acc[i][j]);                    \
  }

// plain GEMM: C[M][N] = A[M][K] * B[N][K]^T, C fp32
__global__ __launch_bounds__(256) void gemm_bt(const u16* __restrict__ A, const u16* __restrict__ B,
                                               float* __restrict__ C, int M, int N, int K) {
  __shared__ u16 sA[2][128][64];  // 32 KB
  __shared__ u16 sB[2][64][64];   // 16 KB
  const int tid = threadIdx.x;
  const int wave = tid >> 6, lane = tid & 63;
  const int bm = blockIdx.y * 128, bn = blockIdx.x * 64;
  const int lr = lane & 15, lk = (lane >> 4) * 8;
  const int wr = wave * 32;
  (void)lk;

  f32x4 acc[2][4] = {};
  GEMM_MAINLOOP(A, B, K, bm, bn)

  const int crb = (lane >> 4) * 4;
#pragma unroll
  for (int i = 0; i < 2; ++i)
#pragma unroll
    for (int j = 0; j < 4; ++j)
#pragma unroll
      for (int r = 0; r < 4; ++r) {
        int row = bm + wr + i * 16 + crb + r;
        int col = bn + j * 16 + lr;
        C[(size_t)row * N + col] = acc[i][j][r];
      }
}

// ---------------------------------------------------------------- gemm1 fused: qkv-proj + RoPE + scatter
#define QSCALE 0.18033688011112042f  // 0.125 * 1.4426950408889634
__global__ __launch_bounds__(256) void gemm1_fused(const u16* __restrict__ A, const u16* __restrict__ B,
                                                   const float* __restrict__ fc,
                                                   u16* __restrict__ qo, u16* __restrict__ ko,
                                                   u16* __restrict__ vt) {
  __shared__ u16 sA[2][128][64];
  __shared__ u16 sB[2][64][64];
  const int tid = threadIdx.x;
  const int wave = tid >> 6, lane = tid & 63;
  const int bm = blockIdx.y * 128, bn = blockIdx.x * 64;
  const int lr = lane & 15, lk = (lane >> 4) * 8;
  const int wr = wave * 32;
  (void)lk;

  f32x4 acc[2][4] = {};
  GEMM_MAINLOOP(A, B, D, bm, bn)

  const int crb = (lane >> 4) * 4;

  if (bn < 2560) {
    // Q or K: apply RoPE via lane-pair shuffle, store bf16 [h][s][d]
    const bool isQ = (bn < 2048);
    u16* dst_base = isQ ? (qo + (size_t)(bn >> 6) * S * HD)
                        : (ko + (size_t)((bn - 2048) >> 6) * S * HD);
    const float scale = isQ ? QSCALE : 1.0f;
    const int odd = lr & 1;
#pragma unroll
    for (int i = 0; i < 2; ++i)
#pragma unroll
      for (int r = 0; r < 4; ++r) {
        const int srow = bm + wr + i * 16 + crb + r;
#pragma unroll
        for (int j = 0; j < 4; ++j) {
          const int d = j * 16 + lr;
          float x = acc[i][j][r];
          float xp = __shfl_xor(x, 1, 64);  // partner within rope pair
          float2 cs = *(const float2*)(fc + (size_t)srow * 64 + (d >> 1) * 2);
          float y = odd ? (x * cs.x + xp * cs.y) : (x * cs.x - xp * cs.y);
          dst_base[(size_t)srow * HD + d] = f2bf(y * scale);
        }
      }
  } else {
    // V: transpose 128(s) x 64(d) tile via LDS (alias dead sA), store vt[kvh][d][s]
    const int kvh = (bn - 2560) >> 6;
    __syncthreads();  // everyone done reading sA
    u16(*sT)[136] = (u16(*)[136]) & sA[0][0][0];
#pragma unroll
    for (int i = 0; i < 2; ++i)
#pragma unroll
      for (int j = 0; j < 4; ++j)
#pragma unroll
        for (int r = 0; r < 4; ++r)
          sT[j * 16 + lr][wr + i * 16 + crb + r] = f2bf(acc[i][j][r]);
    __syncthreads();
    const int d = tid >> 2, sc = (tid & 3) * 32;
    uint4* dst = (uint4*)(vt + (size_t)kvh * HD * S + (size_t)d * S + bm + sc);
    const uint4* src = (const uint4*)(&sT[d][sc]);
    dst[0] = src[0];
    dst[1] = src[1];
    dst[2] = src[2];
    dst[3] = src[3];
  }
}

// ---------------------------------------------------------------- flash attention, balanced span-pairs
// Wave owns span t and mirror 127-t: uniform ~33 iterations. Full K-range per
// wave -> in-register softmax sum -> direct bf16 out.
//
// v4 (this round): DOUBLE-BUFFERED sK/sV -> ONE barrier per K-tile (was 2;
// the second barrier only protected single-buffered LDS from next-iter
// stores). Stores of tile i+1 go to buf^1 while tile i is read from buf.
// Also: f32x4 softmax denominator (4 indep chains, was 16 chained scalar
// adds = ~128cy of pure latency per iter) and s_setprio(1) around MFMA
// clusters (T5; waves here are phase-skewed so priority arbitration pays).
__global__ __launch_bounds__(256, 2) void attn_kernel(const u16* __restrict__ Q, const u16* __restrict__ Kc,
                                                      const u16* __restrict__ Vt, u16* __restrict__ Out) {
  __shared__ u16 sK[2][64][72];
  __shared__ u16 sV[2][64][72];

  const int p = blockIdx.x;
  const int h = blockIdx.y;
  const int kvh = h >> 2;
  const int tid = threadIdx.x;
  const int wave = tid >> 6, lane = tid & 63;
  const int lr = lane & 15;
  const int lk = (lane >> 4) * 8;
  const int crb = (lane >> 4) * 4;
  const int t = 4 * p + wave;        // 0..63
  const int qbA = 16 * t;            // small span
  const int qbB = 16 * (127 - t);    // mirror span

  const u16* qpA = Q + ((size_t)h * S + qbA + lr) * HD;
  const u16* qpB = Q + ((size_t)h * S + qbB + lr) * HD;
  bf16x8 aA0 = *(const bf16x8*)(qpA + lk);
  bf16x8 aA1 = *(const bf16x8*)(qpA + 32 + lk);
  bf16x8 aB0 = *(const bf16x8*)(qpB + lk);
  bf16x8 aB1 = *(const bf16x8*)(qpB + 32 + lk);

  const u16* Kh = Kc + (size_t)kvh * S * HD;
  const u16* Vh = Vt + (size_t)kvh * HD * S;

  const int sr0 = tid >> 3, so0 = (tid & 7) * 8;
  const int sr1 = sr0 + 32;

  f32x4 lAv = {}, lBv = {};
  f32x4 oA[4] = {}, oB[4] = {};

  const int kend = (32 - p) * 64;

  // prologue: load + stage tile 0 into buf 0
  uint4 pk0 = *(const uint4*)(Kh + (size_t)sr0 * HD + so0);
  uint4 pk1 = *(const uint4*)(Kh + (size_t)sr1 * HD + so0);
  uint4 pv0 = *(const uint4*)(Vh + (size_t)sr0 * S + so0);
  uint4 pv1 = *(const uint4*)(Vh + (size_t)sr1 * S + so0);
  *(uint4*)(&sK[0][sr0][so0]) = pk0;
  *(uint4*)(&sK[0][sr1][so0]) = pk1;
  *(uint4*)(&sV[0][sr0][so0]) = pv0;
  *(uint4*)(&sV[0][sr1][so0]) = pv1;
  __syncthreads();

  bf16x8 vf[4][2];        // V-fragments of the current tile (consumed next iter)
  bf16x8 pfB[2], pfA[2];  // P-fragments of the previous tile
  bool prevA = false;

  for (int kb = 0; kb < kend; kb += 64) {
    const int buf = (kb >> 6) & 1;
    const int kn = kb + 64;
    const bool hasNext = (kn < kend);

    // prefetch next tile into registers (global); consumed by stores below
    if (hasNext) {
      pk0 = *(const uint4*)(Kh + (size_t)(kn + sr0) * HD + so0);
      pk1 = *(const uint4*)(Kh + (size_t)(kn + sr1) * HD + so0);
      pv0 = *(const uint4*)(Vh + (size_t)sr0 * S + kn + so0);
      pv1 = *(const uint4*)(Vh + (size_t)sr1 * S + kn + so0);
    }

    // ---- lagged PV(prev): pure-register MFMAs, fill QK's ds_read latency ----
    if (kb > 0) {
      __builtin_amdgcn_s_setprio(1);
#pragma unroll
      for (int tt = 0; tt < 4; ++tt) {
        oB[tt] = MFMA16(pfB[0], vf[tt][0], oB[tt]);
        oB[tt] = MFMA16(pfB[1], vf[tt][1], oB[tt]);
      }
      if (prevA) {
#pragma unroll
        for (int tt = 0; tt < 4; ++tt) {
          oA[tt] = MFMA16(pfA[0], vf[tt][0], oA[tt]);
          oA[tt] = MFMA16(pfA[1], vf[tt][1], oA[tt]);
        }
      }
      __builtin_amdgcn_s_setprio(0);
    }

    const bool liveA = (kb <= qbA + 15);  // wave-uniform

    // ---- swapped QK^T: out row = k_local (crb+r within tt), col = q = lr ----
    f32x4 cA[4], cB[4];
    __builtin_amdgcn_s_setprio(1);
#pragma unroll
    for (int tt = 0; tt < 4; ++tt) {
      bf16x8 b0 = *(const bf16x8*)(&sK[buf][tt * 16 + lr][lk]);
      bf16x8 b1 = *(const bf16x8*)(&sK[buf][tt * 16 + lr][32 + lk]);
      f32x4 zB = {};
      zB = MFMA16(b0, aB0, zB);
      cB[tt] = MFMA16(b1, aB1, zB);
      if (liveA) {
        f32x4 zA = {};
        zA = MFMA16(b0, aA0, zA);
        cA[tt] = MFMA16(b1, aA1, zA);
      }
    }
    __builtin_amdgcn_s_setprio(0);

    // ---- issue V-fragment reads now; exp2/pack VALU below hides latency ----
#pragma unroll
    for (int tt = 0; tt < 4; ++tt) {
      vf[tt][0] = *(const bf16x8*)(&sV[buf][tt * 16 + lr][lk]);
      vf[tt][1] = *(const bf16x8*)(&sV[buf][tt * 16 + lr][32 + lk]);
    }

    // ---- mirror tile softmax (lane-local row slice) ----
    {
      f32x4 pB[4];
      if (kb + 63 <= qbB) {
#pragma unroll
        for (int tt = 0; tt < 4; ++tt) {
#pragma unroll
          for (int r = 0; r < 4; ++r) pB[tt][r] = EXP2(cB[tt][r] - 8.0f);
          lBv += pB[tt];
        }
      } else {
        const int q = qbB + lr;
#pragma unroll
        for (int tt = 0; tt < 4; ++tt) {
#pragma unroll
          for (int r = 0; r < 4; ++r) {
            const int k = kb + tt * 16 + crb + r;
            pB[tt][r] = (k <= q) ? EXP2(cB[tt][r] - 8.0f) : 0.0f;
          }
          lBv += pB[tt];
        }
      }
      pfB[0] = pack4(pB[0], pB[1]);
      pfB[1] = pack4(pB[2], pB[3]);
    }

    // ---- small tile softmax ----
    if (liveA) {
      f32x4 pA[4];
      if (kb + 63 <= qbA) {
#pragma unroll
        for (int tt = 0; tt < 4; ++tt) {
#pragma unroll
          for (int r = 0; r < 4; ++r) pA[tt][r] = EXP2(cA[tt][r] - 8.0f);
          lAv += pA[tt];
        }
      } else {
        const int q = qbA + lr;
#pragma unroll
        for (int tt = 0; tt < 4; ++tt) {
#pragma unroll
          for (int r = 0; r < 4; ++r) {
            const int k = kb + tt * 16 + crb + r;
            pA[tt][r] = (k <= q) ? EXP2(cA[tt][r] - 8.0f) : 0.0f;
          }
          lAv += pA[tt];
        }
      }
      pfA[0] = pack4(pA[0], pA[1]);
      pfA[1] = pack4(pA[2], pA[3]);
    }

    // ---- stage next tile into the other buffer (no WAR: readers use buf) ----
    if (hasNext) {
      *(uint4*)(&sK[buf ^ 1][sr0][so0]) = pk0;
      *(uint4*)(&sK[buf ^ 1][sr1][so0]) = pk1;
      *(uint4*)(&sV[buf ^ 1][sr0][so0]) = pv0;
      *(uint4*)(&sV[buf ^ 1][sr1][so0]) = pv1;
    }
    prevA = liveA;
    __syncthreads();
  }

  // drain the pipeline: PV of the final tile
  __builtin_amdgcn_s_setprio(1);
#pragma unroll
  for (int tt = 0; tt < 4; ++tt) {
    oB[tt] = MFMA16(pfB[0], vf[tt][0], oB[tt]);
    oB[tt] = MFMA16(pfB[1], vf[tt][1], oB[tt]);
  }
  if (prevA) {
#pragma unroll
    for (int tt = 0; tt < 4; ++tt) {
      oA[tt] = MFMA16(pfA[0], vf[tt][0], oA[tt]);
      oA[tt] = MFMA16(pfA[1], vf[tt][1], oA[tt]);
    }
  }
  __builtin_amdgcn_s_setprio(0);

  // epilogue: denominators live per-lane (q = lr); reduce across hi groups
  float lA = lAv[0] + lAv[1] + lAv[2] + lAv[3];
  float lB = lBv[0] + lBv[1] + lBv[2] + lBv[3];
  lA += __shfl_xor(lA, 16, 64);
  lA += __shfl_xor(lA, 32, 64);
  lB += __shfl_xor(lB, 16, 64);
  lB += __shfl_xor(lB, 32, 64);
  float rA[4], rB[4];
#pragma unroll
  for (int r = 0; r < 4; ++r) {
    rA[r] = 1.0f / __shfl(lA, crb + r, 64);
    rB[r] = 1.0f / __shfl(lB, crb + r, 64);
  }
#pragma unroll
  for (int tt = 0; tt < 4; ++tt)
#pragma unroll
    for (int r = 0; r < 4; ++r) {
      const int d = tt * 16 + lr;
      Out[(size_t)(qbA + crb + r) * D + h * HD + d] = f2bf(oA[tt][r] * rA[r]);
      Out[(size_t)(qbB + crb + r) * D + h * HD + d] = f2bf(oB[tt][r] * rB[r]);
    }
}

// ---------------------------------------------------------------- launch
extern "C" void kernel_launch(void* const* d_in, const int* in_sizes, int n_in,
                              void* d_out, int out_size, void* d_ws, size_t ws_size,
                              hipStream_t stream) {
  const float* hs = (const float*)d_in[0];
  const float* fc = (const float*)d_in[1];
  const float* wqkv = (const float*)d_in[2];
  const float* wo = (const float*)d_in[3];
  float* out = (float*)d_out;
  char* ws = (char*)d_ws;

  // Workspace (peak 48 MB):
  u16* hs_bf   = (u16*)(ws);                          // [0,8)
  u16* wqkv_bf = (u16*)(ws + ((size_t)8 << 20));      // [8,20)
  u16* wo_bf   = (u16*)(ws + ((size_t)20 << 20));     // [20,28)
  u16* q_bf    = (u16*)(ws + ((size_t)28 << 20));     // [28,36)
  u16* k_bf    = (u16*)(ws + ((size_t)36 << 20));     // [36,38)
  u16* vt_bf   = (u16*)(ws + ((size_t)38 << 20));     // [38,40)
  u16* attn_bf = (u16*)(ws + ((size_t)40 << 20));     // [40,48)

  cast_all<<<(N1 + N2 + N3 + 255) / 256, 256, 0, stream>>>(hs, wqkv, wo, hs_bf, wqkv_bf, wo_bf);

  // fused qkv-proj + rope + scatter (2048 x 3072 x 2048), 768 blocks
  gemm1_fused<<<dim3(QKV_N / 64, S / 128), 256, 0, stream>>>(hs_bf, wqkv_bf, fc, q_bf, k_bf, vt_bf);

  // balanced span-pair attention, 512 blocks, direct bf16 output
  attn_kernel<<<dim3(16, NH), 256, 0, stream>>>(q_bf, k_bf, vt_bf, attn_bf);

  // out = attn @ wo^T  (2048 x 2048 x 2048), 512 blocks
  gemm_bt<<<dim3(D / 64, S / 128), 256, 0, stream>>>(attn_bf, wo_bf, out, S, D, D);
}

// Round 4
// 194.756 us; speedup vs baseline: 1.0345x; 1.0345x over previous
//
#include <hip/hip_runtime.h>

typedef unsigned short u16;
typedef __attribute__((ext_vector_type(8))) short bf16x8;
typedef __attribute__((ext_vector_type(4))) float f32x4;

#define MFMA16(a, b, c) __builtin_amdgcn_mfma_f32_16x16x32_bf16((a), (b), (c), 0, 0, 0)
#define EXP2(x) __builtin_amdgcn_exp2f(x)

// Problem constants
#define S 2048
#define D 2048
#define NH 32
#define NKV 8
#define HD 64
#define QKV_N 3072  // (32 + 2*8) * 64

__device__ __forceinline__ u16 f2bf(float f) {
  unsigned int u = __float_as_uint(f);
  u += 0x7fffu + ((u >> 16) & 1u);
  return (u16)(u >> 16);
}

// async global->LDS, 16B per lane. LDS dest = wave-uniform base + lane*16.
__device__ __forceinline__ void glds16(const void* g, void* l) {
  __builtin_amdgcn_global_load_lds((const __attribute__((address_space(1))) unsigned int*)g,
                                   (__attribute__((address_space(3))) unsigned int*)l,
                                   16, 0, 0);
}

// ---- T12 primitives: pack f32 P-values to bf16 PV A-fragment in-register ----
__device__ __forceinline__ unsigned int cvtpk(float lo, float hi) {
  unsigned int r;
  asm("v_cvt_pk_bf16_f32 %0, %1, %2" : "=v"(r) : "v"(lo), "v"(hi));
  return r;
}
// swaps lanes[32:63] of a with lanes[0:31] of b (both regs updated)
__device__ __forceinline__ void swap32(unsigned int& a, unsigned int& b) {
  asm("v_permlane32_swap_b32 %0, %1" : "+v"(a), "+v"(b));
}
// swaps odd 16-lane rows of a with even 16-lane rows of b
__device__ __forceinline__ void swap16(unsigned int& a, unsigned int& b) {
  asm("v_permlane16_swap_b32 %0, %1" : "+v"(a), "+v"(b));
}
// Input: c0[r] = P[q=lr][k = t0*16 + 4*hi + r], c1[r] = same at t0*16+16.
// Output: bf16x8 A-fragment, elem j = P[q=lr][k = t0*16 + 8*hi + j].
__device__ __forceinline__ bf16x8 pack4(const f32x4 c0, const f32x4 c1) {
  unsigned int x0 = cvtpk(c0[0], c0[1]);  // {4hi,4hi+1}
  unsigned int x1 = cvtpk(c0[2], c0[3]);  // {4hi+2,4hi+3}
  unsigned int y0 = cvtpk(c1[0], c1[1]);  // {16+4hi,16+4hi+1}
  unsigned int y1 = cvtpk(c1[2], c1[3]);  // {16+4hi+2,16+4hi+3}
  swap32(x0, y0); swap16(x0, y0);  // x0 -> {8hi,8hi+1}, y0 -> {8hi+4,8hi+5}
  swap32(x1, y1); swap16(x1, y1);  // x1 -> {8hi+2,8hi+3}, y1 -> {8hi+6,8hi+7}
  union { bf16x8 v; unsigned int u[4]; } r;
  r.u[0] = x0; r.u[1] = x1; r.u[2] = y0; r.u[3] = y1;
  return r.v;
}

// ---------------------------------------------------------------- fused cast fp32 -> bf16 (all 3 inputs)
#define N1 (S * D / 4)
#define N2 (QKV_N * D / 4)
#define N3 (D * D / 4)
__global__ void cast_all(const float* __restrict__ hs, const float* __restrict__ wqkv,
                         const float* __restrict__ wo, u16* __restrict__ o1,
                         u16* __restrict__ o2, u16* __restrict__ o3) {
  int i = blockIdx.x * blockDim.x + threadIdx.x;
  const float* src;
  u16* dst;
  int idx;
  if (i < N1) { src = hs; dst = o1; idx = i; }
  else if (i < N1 + N2) { src = wqkv; dst = o2; idx = i - N1; }
  else if (i < N1 + N2 + N3) { src = wo; dst = o3; idx = i - N1 - N2; }
  else return;
  float4 v = ((const float4*)src)[idx];
  ushort4 o;
  o.x = f2bf(v.x); o.y = f2bf(v.y); o.z = f2bf(v.z); o.w = f2bf(v.w);
  ((ushort4*)dst)[idx] = o;
}

// ---------------------------------------------------------------- GEMM core: 128x64 tile, BK=64, glds dbuf
// One barrier per 64-wide K-step. XOR-SWIZZLED LDS layout: rows are 128 B =
// exactly 32 banks, so the naive layout puts all 16 rows of a fragment read
// on the same 4 banks (16-way conflict, ~5.7x per ds_read_b128 -- measured
// 1.4e7 SQ_LDS_BANK_CONFLICT in R8). global_load_lds forbids padding (dest
// is lane-contiguous), but the SOURCE is per-lane: stage global 16B-chunk
// (c ^ row&7) into physical chunk c. Readers XOR the chunk index with row&7:
// 16 rows -> 8 distinct chunks = all 32 banks, 2-way only (free, m136).
#define GEMM_MAINLOOP(A_, B_, K_, bm_, bn_)                                            \
  const int srowS = lane >> 3, scolS = ((lane & 7) ^ srowS) * 8;                       \
  const int aBase = wave * 32, bBase = wave * 16;                                      \
  const int qq = lane >> 4, sw = lr & 7;                                               \
  _Pragma("unroll") for (int c2 = 0; c2 < 4; ++c2)                                     \
      glds16(A_ + (size_t)(bm_ + aBase + c2 * 8 + srowS) * K_ + scolS,                 \
             &sA[0][aBase + c2 * 8][0]);                                               \
  _Pragma("unroll") for (int c2 = 0; c2 < 2; ++c2)                                     \
      glds16(B_ + (size_t)(bn_ + bBase + c2 * 8 + srowS) * K_ + scolS,                 \
             &sB[0][bBase + c2 * 8][0]);                                               \
  const int nk = K_ >> 6;                                                              \
  for (int it = 0; it < nk; ++it) {                                                    \
    const int buf = it & 1;                                                            \
    __syncthreads();                                                                   \
    if (it + 1 < nk) {                                                                 \
      const int k1 = (it + 1) << 6;                                                    \
      _Pragma("unroll") for (int c2 = 0; c2 < 4; ++c2)                                 \
          glds16(A_ + (size_t)(bm_ + aBase + c2 * 8 + srowS) * K_ + k1 + scolS,        \
                 &sA[buf ^ 1][aBase + c2 * 8][0]);                                     \
      _Pragma("unroll") for (int c2 = 0; c2 < 2; ++c2)                                 \
          glds16(B_ + (size_t)(bn_ + bBase + c2 * 8 + srowS) * K_ + k1 + scolS,        \
                 &sB[buf ^ 1][bBase + c2 * 8][0]);                                     \
    }                                                                                  \
    bf16x8 af[2][2], bfr[2][4];                                                        \
    _Pragma("unroll") for (int c = 0; c < 2; ++c) {                                    \
      const int pc = (((c << 2) | qq) ^ sw) * 8; /* swizzled chunk -> u16 offset */    \
      _Pragma("unroll") for (int i = 0; i < 2; ++i)                                    \
          af[c][i] = *(const bf16x8*)(&sA[buf][wr + i * 16 + lr][pc]);                 \
      _Pragma("unroll") for (int j = 0; j < 4; ++j)                                    \
          bfr[c][j] = *(const bf16x8*)(&sB[buf][j * 16 + lr][pc]);                     \
    }                                                                                  \
    _Pragma("unroll") for (int c = 0; c < 2; ++c)                                      \
        _Pragma("unroll") for (int i = 0; i < 2; ++i)                                  \
            _Pragma("unroll") for (int j = 0; j < 4; ++j)                              \
                acc[i][j] = MFMA16(af[c][i], bfr[c][j], acc[i][j]);                    \
  }

// plain GEMM: C[M][N] = A[M][K] * B[N][K]^T, C fp32
__global__ __launch_bounds__(256) void gemm_bt(const u16* __restrict__ A, const u16* __restrict__ B,
                                               float* __restrict__ C, int M, int N, int K) {
  __shared__ u16 sA[2][128][64];  // 32 KB
  __shared__ u16 sB[2][64][64];   // 16 KB
  const int tid = threadIdx.x;
  const int wave = tid >> 6, lane = tid & 63;
  const int bm = blockIdx.y * 128, bn = blockIdx.x * 64;
  const int lr = lane & 15, lk = (lane >> 4) * 8;
  const int wr = wave * 32;
  (void)lk;

  f32x4 acc[2][4] = {};
  GEMM_MAINLOOP(A, B, K, bm, bn)

  const int crb = (lane >> 4) * 4;
#pragma unroll
  for (int i = 0; i < 2; ++i)
#pragma unroll
    for (int j = 0; j < 4; ++j)
#pragma unroll
      for (int r = 0; r < 4; ++r) {
        int row = bm + wr + i * 16 + crb + r;
        int col = bn + j * 16 + lr;
        C[(size_t)row * N + col] = acc[i][j][r];
      }
}

// ---------------------------------------------------------------- gemm1 fused: qkv-proj + RoPE + scatter
#define QSCALE 0.18033688011112042f  // 0.125 * 1.4426950408889634
__global__ __launch_bounds__(256) void gemm1_fused(const u16* __restrict__ A, const u16* __restrict__ B,
                                                   const float* __restrict__ fc,
                                                   u16* __restrict__ qo, u16* __restrict__ ko,
                                                   u16* __restrict__ vt) {
  __shared__ u16 sA[2][128][64];
  __shared__ u16 sB[2][64][64];
  const int tid = threadIdx.x;
  const int wave = tid >> 6, lane = tid & 63;
  const int bm = blockIdx.y * 128, bn = blockIdx.x * 64;
  const int lr = lane & 15, lk = (lane >> 4) * 8;
  const int wr = wave * 32;
  (void)lk;

  f32x4 acc[2][4] = {};
  GEMM_MAINLOOP(A, B, D, bm, bn)

  const int crb = (lane >> 4) * 4;

  if (bn < 2560) {
    // Q or K: apply RoPE via lane-pair shuffle, store bf16 [h][s][d]
    const bool isQ = (bn < 2048);
    u16* dst_base = isQ ? (qo + (size_t)(bn >> 6) * S * HD)
                        : (ko + (size_t)((bn - 2048) >> 6) * S * HD);
    const float scale = isQ ? QSCALE : 1.0f;
    const int odd = lr & 1;
#pragma unroll
    for (int i = 0; i < 2; ++i)
#pragma unroll
      for (int r = 0; r < 4; ++r) {
        const int srow = bm + wr + i * 16 + crb + r;
#pragma unroll
        for (int j = 0; j < 4; ++j) {
          const int d = j * 16 + lr;
          float x = acc[i][j][r];
          float xp = __shfl_xor(x, 1, 64);  // partner within rope pair
          float2 cs = *(const float2*)(fc + (size_t)srow * 64 + (d >> 1) * 2);
          float y = odd ? (x * cs.x + xp * cs.y) : (x * cs.x - xp * cs.y);
          dst_base[(size_t)srow * HD + d] = f2bf(y * scale);
        }
      }
  } else {
    // V: transpose 128(s) x 64(d) tile via LDS (alias dead sA), store vt[kvh][d][s]
    const int kvh = (bn - 2560) >> 6;
    __syncthreads();  // everyone done reading sA
    u16(*sT)[136] = (u16(*)[136]) & sA[0][0][0];
#pragma unroll
    for (int i = 0; i < 2; ++i)
#pragma unroll
      for (int j = 0; j < 4; ++j)
#pragma unroll
        for (int r = 0; r < 4; ++r)
          sT[j * 16 + lr][wr + i * 16 + crb + r] = f2bf(acc[i][j][r]);
    __syncthreads();
    const int d = tid >> 2, sc = (tid & 3) * 32;
    uint4* dst = (uint4*)(vt + (size_t)kvh * HD * S + (size_t)d * S + bm + sc);
    const uint4* src = (const uint4*)(&sT[d][sc]);
    dst[0] = src[0];
    dst[1] = src[1];
    dst[2] = src[2];
    dst[3] = src[3];
  }
}

// ---------------------------------------------------------------- flash attention, balanced span-pairs
// Wave owns span t and mirror 127-t: uniform ~33 iterations. Full K-range per
// wave -> in-register softmax sum -> direct bf16 out.
//
// v5 (this round): COMPLEMENTARY-P SWIZZLE for per-CU load balance.
// Grid is 512 blocks on 256 CUs = exactly 2 blocks/CU, and block p runs
// 32-p iterations. Linearized blockIdx = h*16 + p, and blocks b / b+256
// (round-robin onto the same CU) had the SAME p -> per-CU work spanned
// 2x17=34 .. 2x32=64 iteration-units; the wall was set by p=0 CUs (64)
// while the mean was 49 (~23% tail waste). Remap: for h >= 16 use
// p_eff = 15 - blockIdx.x. Coverage of (p,h) stays a bijection and the
// two co-resident blocks now have p and 15-p: per-CU work = 64-15 = 49,
// constant across ALL CUs.
__global__ __launch_bounds__(256, 2) void attn_kernel(const u16* __restrict__ Q, const u16* __restrict__ Kc,
                                                      const u16* __restrict__ Vt, u16* __restrict__ Out) {
  __shared__ u16 sK[2][64][72];
  __shared__ u16 sV[2][64][72];

  const int h = blockIdx.y;
  const int p = (h >= 16) ? (15 - blockIdx.x) : blockIdx.x;  // complementary-p pairing
  const int kvh = h >> 2;
  const int tid = threadIdx.x;
  const int wave = tid >> 6, lane = tid & 63;
  const int lr = lane & 15;
  const int lk = (lane >> 4) * 8;
  const int crb = (lane >> 4) * 4;
  const int t = 4 * p + wave;        // 0..63
  const int qbA = 16 * t;            // small span
  const int qbB = 16 * (127 - t);    // mirror span

  const u16* qpA = Q + ((size_t)h * S + qbA + lr) * HD;
  const u16* qpB = Q + ((size_t)h * S + qbB + lr) * HD;
  bf16x8 aA0 = *(const bf16x8*)(qpA + lk);
  bf16x8 aA1 = *(const bf16x8*)(qpA + 32 + lk);
  bf16x8 aB0 = *(const bf16x8*)(qpB + lk);
  bf16x8 aB1 = *(const bf16x8*)(qpB + 32 + lk);

  const u16* Kh = Kc + (size_t)kvh * S * HD;
  const u16* Vh = Vt + (size_t)kvh * HD * S;

  const int sr0 = tid >> 3, so0 = (tid & 7) * 8;
  const int sr1 = sr0 + 32;

  f32x4 lAv = {}, lBv = {};
  f32x4 oA[4] = {}, oB[4] = {};

  const int kend = (32 - p) * 64;

  // prologue: load + stage tile 0 into buf 0
  uint4 pk0 = *(const uint4*)(Kh + (size_t)sr0 * HD + so0);
  uint4 pk1 = *(const uint4*)(Kh + (size_t)sr1 * HD + so0);
  uint4 pv0 = *(const uint4*)(Vh + (size_t)sr0 * S + so0);
  uint4 pv1 = *(const uint4*)(Vh + (size_t)sr1 * S + so0);
  *(uint4*)(&sK[0][sr0][so0]) = pk0;
  *(uint4*)(&sK[0][sr1][so0]) = pk1;
  *(uint4*)(&sV[0][sr0][so0]) = pv0;
  *(uint4*)(&sV[0][sr1][so0]) = pv1;
  __syncthreads();

  bf16x8 vf[4][2];        // V-fragments of the current tile (consumed next iter)
  bf16x8 pfB[2], pfA[2];  // P-fragments of the previous tile
  bool prevA = false;

  for (int kb = 0; kb < kend; kb += 64) {
    const int buf = (kb >> 6) & 1;
    const int kn = kb + 64;
    const bool hasNext = (kn < kend);

    // prefetch next tile into registers (global); consumed by stores below
    if (hasNext) {
      pk0 = *(const uint4*)(Kh + (size_t)(kn + sr0) * HD + so0);
      pk1 = *(const uint4*)(Kh + (size_t)(kn + sr1) * HD + so0);
      pv0 = *(const uint4*)(Vh + (size_t)sr0 * S + kn + so0);
      pv1 = *(const uint4*)(Vh + (size_t)sr1 * S + kn + so0);
    }

    // ---- lagged PV(prev): pure-register MFMAs, fill QK's ds_read latency ----
    if (kb > 0) {
      __builtin_amdgcn_s_setprio(1);
#pragma unroll
      for (int tt = 0; tt < 4; ++tt) {
        oB[tt] = MFMA16(pfB[0], vf[tt][0], oB[tt]);
        oB[tt] = MFMA16(pfB[1], vf[tt][1], oB[tt]);
      }
      if (prevA) {
#pragma unroll
        for (int tt = 0; tt < 4; ++tt) {
          oA[tt] = MFMA16(pfA[0], vf[tt][0], oA[tt]);
          oA[tt] = MFMA16(pfA[1], vf[tt][1], oA[tt]);
        }
      }
      __builtin_amdgcn_s_setprio(0);
    }

    const bool liveA = (kb <= qbA + 15);  // wave-uniform

    // ---- swapped QK^T: out row = k_local (crb+r within tt), col = q = lr ----
    f32x4 cA[4], cB[4];
    __builtin_amdgcn_s_setprio(1);
#pragma unroll
    for (int tt = 0; tt < 4; ++tt) {
      bf16x8 b0 = *(const bf16x8*)(&sK[buf][tt * 16 + lr][lk]);
      bf16x8 b1 = *(const bf16x8*)(&sK[buf][tt * 16 + lr][32 + lk]);
      f32x4 zB = {};
      zB = MFMA16(b0, aB0, zB);
      cB[tt] = MFMA16(b1, aB1, zB);
      if (liveA) {
        f32x4 zA = {};
        zA = MFMA16(b0, aA0, zA);
        cA[tt] = MFMA16(b1, aA1, zA);
      }
    }
    __builtin_amdgcn_s_setprio(0);

    // ---- issue V-fragment reads now; exp2/pack VALU below hides latency ----
#pragma unroll
    for (int tt = 0; tt < 4; ++tt) {
      vf[tt][0] = *(const bf16x8*)(&sV[buf][tt * 16 + lr][lk]);
      vf[tt][1] = *(const bf16x8*)(&sV[buf][tt * 16 + lr][32 + lk]);
    }

    // ---- mirror tile softmax (lane-local row slice) ----
    {
      f32x4 pB[4];
      if (kb + 63 <= qbB) {
#pragma unroll
        for (int tt = 0; tt < 4; ++tt) {
#pragma unroll
          for (int r = 0; r < 4; ++r) pB[tt][r] = EXP2(cB[tt][r] - 8.0f);
          lBv += pB[tt];
        }
      } else {
        const int q = qbB + lr;
#pragma unroll
        for (int tt = 0; tt < 4; ++tt) {
#pragma unroll
          for (int r = 0; r < 4; ++r) {
            const int k = kb + tt * 16 + crb + r;
            pB[tt][r] = (k <= q) ? EXP2(cB[tt][r] - 8.0f) : 0.0f;
          }
          lBv += pB[tt];
        }
      }
      pfB[0] = pack4(pB[0], pB[1]);
      pfB[1] = pack4(pB[2], pB[3]);
    }

    // ---- small tile softmax ----
    if (liveA) {
      f32x4 pA[4];
      if (kb + 63 <= qbA) {
#pragma unroll
        for (int tt = 0; tt < 4; ++tt) {
#pragma unroll
          for (int r = 0; r < 4; ++r) pA[tt][r] = EXP2(cA[tt][r] - 8.0f);
          lAv += pA[tt];
        }
      } else {
        const int q = qbA + lr;
#pragma unroll
        for (int tt = 0; tt < 4; ++tt) {
#pragma unroll
          for (int r = 0; r < 4; ++r) {
            const int k = kb + tt * 16 + crb + r;
            pA[tt][r] = (k <= q) ? EXP2(cA[tt][r] - 8.0f) : 0.0f;
          }
          lAv += pA[tt];
        }
      }
      pfA[0] = pack4(pA[0], pA[1]);
      pfA[1] = pack4(pA[2], pA[3]);
    }

    // ---- stage next tile into the other buffer (no WAR: readers use buf) ----
    if (hasNext) {
      *(uint4*)(&sK[buf ^ 1][sr0][so0]) = pk0;
      *(uint4*)(&sK[buf ^ 1][sr1][so0]) = pk1;
      *(uint4*)(&sV[buf ^ 1][sr0][so0]) = pv0;
      *(uint4*)(&sV[buf ^ 1][sr1][so0]) = pv1;
    }
    prevA = liveA;
    __syncthreads();
  }

  // drain the pipeline: PV of the final tile
  __builtin_amdgcn_s_setprio(1);
#pragma unroll
  for (int tt = 0; tt < 4; ++tt) {
    oB[tt] = MFMA16(pfB[0], vf[tt][0], oB[tt]);
    oB[tt] = MFMA16(pfB[1], vf[tt][1], oB[tt]);
  }
  if (prevA) {
#pragma unroll
    for (int tt = 0; tt < 4; ++tt) {
      oA[tt] = MFMA16(pfA[0], vf[tt][0], oA[tt]);
      oA[tt] = MFMA16(pfA[1], vf[tt][1], oA[tt]);
    }
  }
  __builtin_amdgcn_s_setprio(0);

  // epilogue: denominators live per-lane (q = lr); reduce across hi groups
  float lA = lAv[0] + lAv[1] + lAv[2] + lAv[3];
  float lB = lBv[0] + lBv[1] + lBv[2] + lBv[3];
  lA += __shfl_xor(lA, 16, 64);
  lA += __shfl_xor(lA, 32, 64);
  lB += __shfl_xor(lB, 16, 64);
  lB += __shfl_xor(lB, 32, 64);
  float rA[4], rB[4];
#pragma unroll
  for (int r = 0; r < 4; ++r) {
    rA[r] = 1.0f / __shfl(lA, crb + r, 64);
    rB[r] = 1.0f / __shfl(lB, crb + r, 64);
  }
#pragma unroll
  for (int tt = 0; tt < 4; ++tt)
#pragma unroll
    for (int r = 0; r < 4; ++r) {
      const int d = tt * 16 + lr;
      Out[(size_t)(qbA + crb + r) * D + h * HD + d] = f2bf(oA[tt][r] * rA[r]);
      Out[(size_t)(qbB + crb + r) * D + h * HD + d] = f2bf(oB[tt][r] * rB[r]);
    }
}

// ---------------------------------------------------------------- launch
extern "C" void kernel_launch(void* const* d_in, const int* in_sizes, int n_in,
                              void* d_out, int out_size, void* d_ws, size_t ws_size,
                              hipStream_t stream) {
  const float* hs = (const float*)d_in[0];
  const float* fc = (const float*)d_in[1];
  const float* wqkv = (const float*)d_in[2];
  const float* wo = (const float*)d_in[3];
  float* out = (float*)d_out;
  char* ws = (char*)d_ws;

  // Workspace (peak 48 MB):
  u16* hs_bf   = (u16*)(ws);                          // [0,8)
  u16* wqkv_bf = (u16*)(ws + ((size_t)8 << 20));      // [8,20)
  u16* wo_bf   = (u16*)(ws + ((size_t)20 << 20));     // [20,28)
  u16* q_bf    = (u16*)(ws + ((size_t)28 << 20));     // [28,36)
  u16* k_bf    = (u16*)(ws + ((size_t)36 << 20));     // [36,38)
  u16* vt_bf   = (u16*)(ws + ((size_t)38 << 20));     // [38,40)
  u16* attn_bf = (u16*)(ws + ((size_t)40 << 20));     // [40,48)

  cast_all<<<(N1 + N2 + N3 + 255) / 256, 256, 0, stream>>>(hs, wqkv, wo, hs_bf, wqkv_bf, wo_bf);

  // fused qkv-proj + rope + scatter (2048 x 3072 x 2048), 768 blocks
  gemm1_fused<<<dim3(QKV_N / 64, S / 128), 256, 0, stream>>>(hs_bf, wqkv_bf, fc, q_bf, k_bf, vt_bf);

  // balanced span-pair attention, 512 blocks, direct bf16 output
  attn_kernel<<<dim3(16, NH), 256, 0, stream>>>(q_bf, k_bf, vt_bf, attn_bf);

  // out = attn @ wo^T  (2048 x 2048 x 2048), 512 blocks
  gemm_bt<<<dim3(D / 64, S / 128), 256, 0, stream>>>(attn_bf, wo_bf, out, S, D, D);
}